// Round 4
// baseline (383.300 us; speedup 1.0000x reference)
//
#include <hip/hip_runtime.h>
#include <cstdint>
#include <cstddef>

#define THREADS 256
#define FTHREADS 512

typedef __attribute__((ext_vector_type(8))) short short8;   // 8 bf16 = 4 VGPR (MFMA A/B frag)
typedef __attribute__((ext_vector_type(4))) float f32x4;    // MFMA C/D frag
typedef __attribute__((ext_vector_type(2))) float f32x2;    // v_pk_fma_f32 pair

#define MFMA(a, b, c) __builtin_amdgcn_mfma_f32_16x16x32_bf16((a), (b), (c), 0, 0, 0)

static constexpr int kC    = 128;
static constexpr int kImgC = 128 * 256;   // 32768 coarse px / image
static constexpr int kImgF = 256 * 512;   // 131072 fine px / image

// fp32 -> bf16 RNE (integer math; inputs are never NaN here)
__device__ __forceinline__ unsigned short f2bf(float f) {
  unsigned u = __builtin_bit_cast(unsigned, f);
  u += 0x7fffu + ((u >> 16) & 1u);
  return (unsigned short)(u >> 16);
}
// pack two floats -> bf16x2 as uint (lo in low half)
__device__ __forceinline__ unsigned pack_bf16(float lo, float hi) {
  return (unsigned)f2bf(lo) | ((unsigned)f2bf(hi) << 16);
}
__device__ __forceinline__ float bf_lo(unsigned u) {
  return __builtin_bit_cast(float, u << 16);
}
__device__ __forceinline__ float bf_hi(unsigned u) {
  return __builtin_bit_cast(float, u & 0xffff0000u);
}
__device__ __forceinline__ f32x2 bf_up2(unsigned u) {
  return (f32x2){bf_lo(u), bf_hi(u)};
}

// A-frag: lane l supplies A[m=px][k=c]: px = mt*16+(l&15), c = kt*32+(l>>4)*8+j
// element (px,c) at byte: px*256 + (((c>>3) ^ (px&7))*16) + (c&7)*2
__device__ __forceinline__ short8 ldA(const char* lds, int mt, int kt, int l) {
  const int px = mt * 16 + (l & 15);
  const int chunk = (kt * 4 + (l >> 4)) ^ (px & 7);
  return *(const short8*)(lds + px * 256 + chunk * 16);
}

// ---------- kernel 0: cast all weights fp32 [o][c] -> bf16 [o][c] ----------
// wbuf layout (shorts): Wq@0(8192) Wk@8192(8192) Wvp@16384(16384) Wvi@32768(16384) Wout@49152(16384)
__global__ __launch_bounds__(THREADS) void cast_w(
    const float* __restrict__ Wq, const float* __restrict__ Wk,
    const float* __restrict__ Wvp, const float* __restrict__ Wvi,
    const float* __restrict__ Wout, unsigned short* __restrict__ dst) {
  int i = blockIdx.x * THREADS + threadIdx.x;   // 0..65535
  float v;
  if (i < 8192)       v = Wq[i];
  else if (i < 16384) v = Wk[i - 8192];
  else if (i < 32768) v = Wvp[i - 16384];
  else if (i < 49152) v = Wvi[i - 32768];
  else                v = Wout[i - 49152];
  dst[i] = f2bf(v);
}

// ---------- kernel 0b: Wfused = Wout @ Wvi (bf16), bfused = Wout@bvi + bout ----------
__global__ __launch_bounds__(THREADS) void fuse_w(
    const float* __restrict__ Wvi, const float* __restrict__ bvi,
    const float* __restrict__ Wout, const float* __restrict__ bout,
    unsigned short* __restrict__ wf, float* __restrict__ bf) {
  const int idx = blockIdx.x * THREADS + threadIdx.x;  // 0..16383
  const int o = idx >> 7, c = idx & 127;
  float s = 0.f;
  #pragma unroll 4
  for (int m2 = 0; m2 < 128; ++m2) s += Wout[o * 128 + m2] * Wvi[m2 * 128 + c];
  wf[idx] = f2bf(s);
  if (c == 0) {
    float sb = bout[o];
    for (int m2 = 0; m2 < 128; ++m2) sb += Wout[o * 128 + m2] * bvi[m2];
    bf[o] = sb;
  }
}

// ---------- kernel 1: coarse k,v via MFMA -> bf16 kbuf/vbuf ----------
// kbuf: [px][64] bf16, vbuf: [px][128] bf16 (px = global coarse pixel)
__global__ __launch_bounds__(THREADS, 4) void coarse_kv(
    const float* __restrict__ h_prev, const unsigned short* __restrict__ wbuf,
    const float* __restrict__ bk, const float* __restrict__ bvp,
    unsigned short* __restrict__ kbuf, unsigned short* __restrict__ vbuf) {
  __shared__ char xs[16384];
  const int tid = threadIdx.x;
  const int l = tid & 63, w = tid >> 6;
  const int m = l & 15, g = l >> 4;
  const int chq = w * 16 + m;

  const int tile = blockIdx.x;              // 0..1023
  const int b    = tile >> 9;
  const int p0   = (tile & 511) * 64;       // within-image coarse px base
  const int p0g  = tile * 64;               // global coarse px base

  const short8* wkp = (const short8*)(wbuf + 8192);
  const short8* wvp = (const short8*)(wbuf + 16384);
  short8 fk[4], fv[2][4];
  #pragma unroll
  for (int kt = 0; kt < 4; ++kt) fk[kt] = wkp[chq * 16 + kt * 4 + g];
  #pragma unroll
  for (int nt = 0; nt < 2; ++nt)
    #pragma unroll
    for (int kt = 0; kt < 4; ++kt)
      fv[nt][kt] = wvp[(nt * 64 + chq) * 16 + kt * 4 + g];

  // stage 64px x 128ch fp32 -> swizzled bf16 A-tile
  {
    const float* src = h_prev + (size_t)b * kC * kImgC + p0;
    const int pxl = l & 7, cg = l >> 3;
    #pragma unroll
    for (int i = 0; i < 16; ++i) {
      const int px = pxl + 8 * (i & 7);
      const int c  = 2 * (cg + 8 * (w + 4 * (i >> 3)));
      float f0 = src[(size_t)c * kImgC + px];
      float f1 = src[(size_t)(c + 1) * kImgC + px];
      const int chunk = (c >> 3) ^ (px & 7);
      *(unsigned*)(xs + px * 256 + chunk * 16 + (c & 7) * 2) = pack_bf16(f0, f1);
    }
  }
  __syncthreads();

  {  // k: 64 out channels
    const float bl = bk[chq];
    #pragma unroll
    for (int mt = 0; mt < 4; ++mt) {
      f32x4 acc = {bl, bl, bl, bl};
      #pragma unroll
      for (int kt = 0; kt < 4; ++kt) acc = MFMA(ldA(xs, mt, kt, l), fk[kt], acc);
      #pragma unroll
      for (int r = 0; r < 4; ++r)
        kbuf[(size_t)(p0g + mt * 16 + g * 4 + r) * 64 + chq] = f2bf(acc[r]);
    }
  }
  #pragma unroll
  for (int nt = 0; nt < 2; ++nt) {  // v: 128 out channels
    const float bl = bvp[nt * 64 + chq];
    #pragma unroll
    for (int mt = 0; mt < 4; ++mt) {
      f32x4 acc = {bl, bl, bl, bl};
      #pragma unroll
      for (int kt = 0; kt < 4; ++kt) acc = MFMA(ldA(xs, mt, kt, l), fv[nt][kt], acc);
      #pragma unroll
      for (int r = 0; r < 4; ++r)
        vbuf[(size_t)(p0g + mt * 16 + g * 4 + r) * 128 + nt * 64 + chq] = f2bf(acc[r]);
    }
  }
}

// ---------- kernel 2: fused fine pass, 8 fine rows x 16 cols per block ----------
// out = Wfused*x + Wout*xatt + bfused (v_init folded into Wfused => no t-RMW).
// accO held in registers across attention; attention writes pure xatt over the
// dead x-tile. Window 6x10 cells staged bf16; attention FMAs packed (f32x2).
__global__ __launch_bounds__(FTHREADS, 4) void fine_fused(
    const float* __restrict__ h_init, const unsigned short* __restrict__ wbuf,
    const unsigned short* __restrict__ wf, const float* __restrict__ bfused,
    const float* __restrict__ bq,
    const unsigned short* __restrict__ kbuf, const unsigned short* __restrict__ vbuf,
    float* __restrict__ out) {
  __shared__ char xs[32768];                 // x-tile (bf16 swz), later xatt-tile
  __shared__ unsigned short qs[128 * 72];    // q  [px][72]        (stride 144 B)
  __shared__ unsigned short ks_[60 * 80];    // k  [cell][4][20]   (sub-stride 40 B)
  __shared__ unsigned short vs_[60 * 144];   // v  [cell][4][36]   (sub-stride 72 B)

  const int tid = threadIdx.x;
  const int l = tid & 63, w = tid >> 6;      // 8 waves
  const int m = l & 15, g = l >> 4;

  const int bid = blockIdx.x;                // 0..2047
  const int b   = bid >> 10;                 // image
  const int r10 = bid & 1023;
  const int ty  = r10 >> 5;                  // tile row 0..31
  const int tx  = r10 & 31;                  // tile col 0..31
  const int y0  = ty * 8;                    // fine row base
  const int x0  = tx * 16;                   // fine col base
  const int y20 = y0 >> 1;                   // coarse row base (4 rows)
  const int x20 = x0 >> 1;                   // coarse col base (8 cols)

  const size_t fbase = (size_t)b * kC * kImgF;
  const unsigned short* kb = kbuf + (size_t)b * kImgC * 64;
  const unsigned short* vb = vbuf + (size_t)b * kImgC * 128;

  const short8* wqp = (const short8*)wbuf;
  const short8* wfp = (const short8*)wf;
  const short8* wop = (const short8*)(wbuf + 49152);

  // ---- stage x-tile: 512 threads, 128 px x 128 ch ----
  {
    const int half = tid >> 8;               // px 0..63 / 64..127
    const int tl = tid & 255;
    const int sl = tl & 63, sw = tl >> 6;
    const int pxl = sl & 7, cg = sl >> 3;
    #pragma unroll
    for (int i = 0; i < 16; ++i) {
      const int px = half * 64 + pxl + 8 * (i & 7);
      const int row = px >> 4, col = px & 15;
      const int c  = 2 * (cg + 8 * (sw + 4 * (i >> 3)));
      const size_t off = (size_t)(y0 + row) * 512 + x0 + col;
      float f0 = h_init[fbase + (size_t)c * kImgF + off];
      float f1 = h_init[fbase + (size_t)(c + 1) * kImgF + off];
      const int chunk = (c >> 3) ^ (px & 7);
      *(unsigned*)(xs + px * 256 + chunk * 16 + (c & 7) * 2) = pack_bf16(f0, f1);
    }
  }

  // ---- stage k window: 60 cells x 16 chunks of 4ch (uint2), zero-fill OOB ----
  #pragma unroll
  for (int it = 0; it < 2; ++it) {
    const int i = tid + it * 512;
    if (i < 960) {
      const int cell = i >> 4, cp = i & 15;
      const int cy = cell / 10, cx = cell - cy * 10;
      const int yy = y20 + cy - 1, xx = x20 + cx - 1;
      uint2 val = make_uint2(0u, 0u);
      if ((unsigned)yy < 128u && (unsigned)xx < 256u)
        val = *(const uint2*)(kb + ((size_t)yy * 256 + xx) * 64 + cp * 4);
      *(uint2*)((char*)ks_ + cell * 160 + (cp >> 2) * 40 + (cp & 3) * 8) = val;
    }
  }
  // ---- stage v window: 60 cells x 32 chunks of 4ch (uint2), zero-fill OOB ----
  #pragma unroll
  for (int it = 0; it < 4; ++it) {
    const int i = tid + it * 512;
    if (i < 1920) {
      const int cell = i >> 5, cp = i & 31;
      const int cy = cell / 10, cx = cell - cy * 10;
      const int yy = y20 + cy - 1, xx = x20 + cx - 1;
      uint2 val = make_uint2(0u, 0u);
      if ((unsigned)yy < 128u && (unsigned)xx < 256u)
        val = *(const uint2*)(vb + ((size_t)yy * 256 + xx) * 128 + cp * 4);
      *(uint2*)((char*)vs_ + cell * 288 + (cp >> 3) * 72 + (cp & 7) * 8) = val;
    }
  }
  __syncthreads();

  // ---- GEMM1: q = x * Wq^T -> qs (bf16). wave: px-half (w>>2), ch-grp ((w&3)*16)
  const int chq4 = (w & 3) * 16 + m;
  const int hh   = w >> 2;
  {
    short8 fq[4];
    #pragma unroll
    for (int kt = 0; kt < 4; ++kt) fq[kt] = wqp[chq4 * 16 + kt * 4 + g];
    const float bl = bq[chq4];
    #pragma unroll
    for (int mt = 0; mt < 4; ++mt) {
      f32x4 acc = {bl, bl, bl, bl};
      #pragma unroll
      for (int kt = 0; kt < 4; ++kt) acc = MFMA(ldA(xs, hh * 4 + mt, kt, l), fq[kt], acc);
      #pragma unroll
      for (int r = 0; r < 4; ++r)
        qs[(hh * 64 + mt * 16 + g * 4 + r) * 72 + chq4] = f2bf(acc[r]);
    }
  }

  // ---- GEMMf: accO = bfused + x * Wfused^T (wave owns ch-group w*16, all 128 px)
  const int ch = w * 16 + m;
  f32x4 accO[8];
  {
    short8 ff[4];
    #pragma unroll
    for (int kt = 0; kt < 4; ++kt) ff[kt] = wfp[ch * 16 + kt * 4 + g];
    const float bl = bfused[ch];
    #pragma unroll
    for (int mt = 0; mt < 8; ++mt) {
      f32x4 acc = {bl, bl, bl, bl};
      #pragma unroll
      for (int kt = 0; kt < 4; ++kt) acc = MFMA(ldA(xs, mt, kt, l), ff[kt], acc);
      accO[mt] = acc;
    }
  }
  __syncthreads();   // all xs(x) reads done; qs visible

  // ---- attention: 4 threads per fine px; all reads from LDS (bf16, pk-f32 FMA) ----
  {
    const int apx = tid >> 2;                // 0..127
    const int sub = tid & 3;
    const int r2  = apx >> 5;                // (row>>1): window row base
    const int c2  = (apx & 15) >> 1;         // window col base

    f32x2 qf2[8];
    {
      const uint4* qp = (const uint4*)((const char*)qs + apx * 144 + sub * 32);
      const uint4 u0 = qp[0], u1 = qp[1];
      const unsigned uu[8] = {u0.x, u0.y, u0.z, u0.w, u1.x, u1.y, u1.z, u1.w};
      #pragma unroll
      for (int i = 0; i < 8; ++i) qf2[i] = bf_up2(uu[i]);
    }

    float a[9];
    #pragma unroll
    for (int j = 0; j < 9; ++j) {
      const int cell = (r2 + j / 3) * 10 + c2 + (j % 3);
      const char* kc = (const char*)ks_ + cell * 160 + sub * 40;
      const uint2 u0 = *(const uint2*)kc;
      const uint2 u1 = *(const uint2*)(kc + 8);
      const uint2 u2 = *(const uint2*)(kc + 16);
      const uint2 u3 = *(const uint2*)(kc + 24);
      const unsigned uu[8] = {u0.x, u0.y, u1.x, u1.y, u2.x, u2.y, u3.x, u3.y};
      f32x2 s2 = {0.f, 0.f};
      #pragma unroll
      for (int i = 0; i < 8; ++i)
        s2 = __builtin_elementwise_fma(qf2[i], bf_up2(uu[i]), s2);
      float s = s2.x + s2.y;
      s += __shfl_xor(s, 1);
      s += __shfl_xor(s, 2);
      a[j] = s;
    }
    float mx = a[0];
    #pragma unroll
    for (int j = 1; j < 9; ++j) mx = fmaxf(mx, a[j]);
    float den = 0.f;
    #pragma unroll
    for (int j = 0; j < 9; ++j) { a[j] = __expf(a[j] - mx); den += a[j]; }
    const float inv = 1.f / den;

    f32x2 tt2[16];
    #pragma unroll
    for (int i = 0; i < 16; ++i) tt2[i] = (f32x2){0.f, 0.f};
    #pragma unroll
    for (int j = 0; j < 9; ++j) {
      const int cell = (r2 + j / 3) * 10 + c2 + (j % 3);
      const float aj = a[j] * inv;
      const f32x2 aj2 = {aj, aj};
      const char* vc = (const char*)vs_ + cell * 288 + sub * 72;
      #pragma unroll
      for (int q2 = 0; q2 < 8; ++q2) {
        const uint2 u = *(const uint2*)(vc + q2 * 8);
        tt2[2 * q2]     = __builtin_elementwise_fma(bf_up2(u.x), aj2, tt2[2 * q2]);
        tt2[2 * q2 + 1] = __builtin_elementwise_fma(bf_up2(u.y), aj2, tt2[2 * q2 + 1]);
      }
    }
    // write xatt (bf16) into xs as swizzled A-tile (x is dead; pure write, no RMW)
    #pragma unroll
    for (int i = 0; i < 16; ++i) {
      const int cc2 = sub * 32 + 2 * i;
      const int chunk = (cc2 >> 3) ^ (apx & 7);
      *(unsigned*)(xs + apx * 256 + chunk * 16 + (cc2 & 7) * 2) =
          pack_bf16(tt2[i].x, tt2[i].y);
    }
  }
  __syncthreads();

  // ---- GEMM3: out = accO + xatt * Wout^T (wave owns ch-group w*16, all 128 px) ----
  {
    short8 fo[4];
    #pragma unroll
    for (int kt = 0; kt < 4; ++kt) fo[kt] = wop[ch * 16 + kt * 4 + g];
    #pragma unroll
    for (int mt = 0; mt < 8; ++mt) {
      f32x4 acc = accO[mt];
      #pragma unroll
      for (int kt = 0; kt < 4; ++kt) acc = MFMA(ldA(xs, mt, kt, l), fo[kt], acc);
      // px = mt*16 + g*4 + r -> row = mt, cols g*4..g*4+3 (contiguous)
      *(float4*)(out + fbase + (size_t)ch * kImgF
                 + (size_t)(y0 + mt) * 512 + x0 + g * 4) =
          make_float4(acc[0], acc[1], acc[2], acc[3]);
    }
  }
}

// ---------- launch ----------
extern "C" void kernel_launch(void* const* d_in, const int* in_sizes, int n_in,
                              void* d_out, int out_size, void* d_ws, size_t ws_size,
                              hipStream_t stream) {
  const float* h_prev = (const float*)d_in[0];
  const float* h_init = (const float*)d_in[1];
  const float* Wq   = (const float*)d_in[2];
  const float* bq   = (const float*)d_in[3];
  const float* Wk   = (const float*)d_in[4];
  const float* bk   = (const float*)d_in[5];
  const float* Wvp  = (const float*)d_in[6];
  const float* bvp  = (const float*)d_in[7];
  const float* Wvi  = (const float*)d_in[8];
  const float* bvi  = (const float*)d_in[9];
  const float* Wout = (const float*)d_in[10];
  const float* bout = (const float*)d_in[11];
  float* out = (float*)d_out;

  char* ws = (char*)d_ws;
  unsigned short* wbuf = (unsigned short*)ws;                    // 131072 B
  unsigned short* wfb  = (unsigned short*)(ws + 131072);         // 32768 B (Wfused)
  float* bfb           = (float*)(ws + 164352 - 512);            // 512 B  (bfused)
  unsigned short* kbuf = (unsigned short*)(ws + 164352);         // 8 MB
  unsigned short* vbuf = (unsigned short*)(ws + 164352 + (size_t)8388608); // 16 MB

  cast_w<<<256, THREADS, 0, stream>>>(Wq, Wk, Wvp, Wvi, Wout, wbuf);
  fuse_w<<<64, THREADS, 0, stream>>>(Wvi, bvi, Wout, bout, wfb, bfb);
  coarse_kv<<<1024, THREADS, 0, stream>>>(h_prev, wbuf, bk, bvp, kbuf, vbuf);
  fine_fused<<<2048, FTHREADS, 0, stream>>>(h_init, wbuf, wfb, bfb, bq,
                                            kbuf, vbuf, out);
}